// Round 1
// baseline (359.349 us; speedup 1.0000x reference)
//
#include <hip/hip_runtime.h>
#include <math.h>

// Problem constants (batch=1024, n=32768), fixed by setup_inputs().
#define NROWS 1024
#define NCOLS 32768
#define NC4   (NCOLS / 4)          // 8192 float4 per row
#define ROWBLK 16                  // k1: row blocks (64 rows each)

// ---------------------------------------------------------------------------
// Threefry-2x32 with key (0, 42)  == jax.random.key(42) raw key data.
// Exact JAX schedule: 5 iterations of 4 rounds; rotations alternate
// (13,15,26,6) / (17,29,16,24); key injections ks[(i+1)%3], ks[(i+2)%3]+i+1.
// ---------------------------------------------------------------------------
__device__ __forceinline__ void tf_round(unsigned &x0, unsigned &x1, int r) {
    x0 += x1;
    x1 = (x1 << r) | (x1 >> (32 - r));
    x1 ^= x0;
}

__device__ __forceinline__ void threefry2x32_key0_42(unsigned &x0, unsigned &x1) {
    const unsigned k0 = 0u;
    const unsigned k1 = 42u;
    const unsigned k2 = 0x1BD11BDAu ^ k0 ^ k1;
    x0 += k0; x1 += k1;
    tf_round(x0, x1, 13); tf_round(x0, x1, 15); tf_round(x0, x1, 26); tf_round(x0, x1, 6);
    x0 += k1; x1 += k2 + 1u;
    tf_round(x0, x1, 17); tf_round(x0, x1, 29); tf_round(x0, x1, 16); tf_round(x0, x1, 24);
    x0 += k2; x1 += k0 + 2u;
    tf_round(x0, x1, 13); tf_round(x0, x1, 15); tf_round(x0, x1, 26); tf_round(x0, x1, 6);
    x0 += k0; x1 += k1 + 3u;
    tf_round(x0, x1, 17); tf_round(x0, x1, 29); tf_round(x0, x1, 16); tf_round(x0, x1, 24);
    x0 += k1; x1 += k2 + 4u;
    tf_round(x0, x1, 13); tf_round(x0, x1, 15); tf_round(x0, x1, 26); tf_round(x0, x1, 6);
    x0 += k2; x1 += k0 + 5u;
}

// ---------------------------------------------------------------------------
// k1: copy x -> out (bitwise) and accumulate per-column |x| partial sums.
// grid (32, ROWBLK), 256 threads. Each block: 1024 columns x 64 rows.
// partial layout: partial[rowblk][col] (ROWBLK * NCOLS floats).
// ---------------------------------------------------------------------------
__global__ __launch_bounds__(256) void k1_copy_colsum(
        const float4* __restrict__ x4, float4* __restrict__ out4,
        float4* __restrict__ partial4) {
    const int t  = threadIdx.x;
    const int j4 = blockIdx.x * 256 + t;         // float4 column index [0, NC4)
    const int r0 = blockIdx.y * (NROWS / ROWBLK);
    float4 acc = make_float4(0.f, 0.f, 0.f, 0.f);
    size_t base = (size_t)r0 * NC4 + j4;
    #pragma unroll 4
    for (int r = 0; r < NROWS / ROWBLK; ++r) {
        float4 v = x4[base];
        out4[base] = v;
        acc.x += fabsf(v.x); acc.y += fabsf(v.y);
        acc.z += fabsf(v.z); acc.w += fabsf(v.w);
        base += NC4;
    }
    partial4[(size_t)blockIdx.y * NC4 + j4] = acc;
}

// ---------------------------------------------------------------------------
// k2: finish column mean, EMA update, ac = exp(-5*a), logits = log(ac),
// block-partial sums of ac. grid 128, 256 threads.
// ---------------------------------------------------------------------------
__global__ __launch_bounds__(256) void k2_logits(
        const float* __restrict__ partial, const float* __restrict__ activ,
        float* __restrict__ logits, float* __restrict__ blocksums) {
    const int t = threadIdx.x;
    const int j = blockIdx.x * 256 + t;
    float s = 0.f;
    #pragma unroll
    for (int rb = 0; rb < ROWBLK; ++rb) s += partial[rb * NCOLS + j];
    float m  = s * (1.0f / (float)NROWS);
    float a  = 0.97f * activ[j] + 0.03f * m;     // EMA buffer update
    float ac = expf(-5.0f * a);
    logits[j] = logf(ac);                        // matches jnp.log(jnp.exp(-5a))
    __shared__ float red[256];
    red[t] = ac;
    __syncthreads();
    for (int off = 128; off > 0; off >>= 1) {
        if (t < off) red[t] += red[t + off];
        __syncthreads();
    }
    if (t == 0) blocksums[blockIdx.x] = red[0];
}

// ---------------------------------------------------------------------------
// k3: s = sum(blocksums); logits[0] = log(s * 4000). 1 block, 128 threads.
// ---------------------------------------------------------------------------
__global__ __launch_bounds__(128) void k3_logit0(
        const float* __restrict__ blocksums, float* __restrict__ logits) {
    const int t = threadIdx.x;
    __shared__ float red[128];
    red[t] = blocksums[t];
    __syncthreads();
    for (int off = 64; off > 0; off >>= 1) {
        if (t < off) red[t] += red[t + off];
        __syncthreads();
    }
    if (t == 0) logits[0] = logf(red[0] * 4000.0f);
}

// ---------------------------------------------------------------------------
// k4: per-row Gumbel argmax (jax.random.categorical, threefry-partitionable
// counter scheme: bits(L) = o0 ^ o1 of threefry((0,42), (0, L)) with L the
// row-major linear index), then out[row, r] += std if r > 0.
// One block per row (1024 blocks), 256 threads, 128 columns/thread.
// First-occurrence tie-break to match jnp.argmax.
// ---------------------------------------------------------------------------
__global__ __launch_bounds__(256) void k4_sample_scatter(
        const float* __restrict__ logits, const float* __restrict__ stdp,
        float* __restrict__ out) {
    const int t   = threadIdx.x;
    const int row = blockIdx.x;
    const unsigned cbase = (unsigned)row * (unsigned)NCOLS;
    float best = -INFINITY;
    int   bi   = 0x7FFFFFFF;

    for (int j = t; j < NCOLS; j += 256) {
        unsigned x0 = 0u;
        unsigned x1 = cbase + (unsigned)j;
        threefry2x32_key0_42(x0, x1);
        unsigned bits = x0 ^ x1;
        // uniform in [tiny, 1):  bitcast((bits>>9)|0x3f800000) - 1, clamp to tiny
        float u = __uint_as_float((bits >> 9) | 0x3f800000u) - 1.0f;
        u = fmaxf(u, 1.17549435e-38f);
        float g = -logf(-logf(u)) + logits[j];   // gumbel + logit
        if (g > best) { best = g; bi = j; }      // strict > keeps earliest j per thread
    }

    __shared__ float sv[256];
    __shared__ int   si[256];
    sv[t] = best; si[t] = bi;
    __syncthreads();
    for (int off = 128; off > 0; off >>= 1) {
        if (t < off) {
            float ov = sv[t + off]; int oi = si[t + off];
            if (ov > sv[t] || (ov == sv[t] && oi < si[t])) { sv[t] = ov; si[t] = oi; }
        }
        __syncthreads();
    }
    if (t == 0) {
        int r = si[0];
        if (r > 0 && r < NCOLS) {
            out[(size_t)row * NCOLS + r] += stdp[0];   // std * (r > 0)
        }
    }
}

// ---------------------------------------------------------------------------
extern "C" void kernel_launch(void* const* d_in, const int* in_sizes, int n_in,
                              void* d_out, int out_size, void* d_ws, size_t ws_size,
                              hipStream_t stream) {
    (void)in_sizes; (void)n_in; (void)out_size; (void)ws_size;
    const float* x     = (const float*)d_in[0];   // [1024, 1, 32768] f32
    const float* activ = (const float*)d_in[1];   // [1, 32768] f32
    const float* stdp  = (const float*)d_in[2];   // [1] f32
    float* out = (float*)d_out;                   // [1024, 1, 32768] f32
    float* ws  = (float*)d_ws;

    // Workspace layout (floats): partial[ROWBLK*NCOLS] | logits[NCOLS] | blocksums[128]
    float* partial   = ws;                        // 16*32768
    float* logits    = ws + ROWBLK * NCOLS;       // 32768
    float* blocksums = logits + NCOLS;            // 128

    dim3 g1(NC4 / 256, ROWBLK);                   // (32, 16)
    k1_copy_colsum<<<g1, 256, 0, stream>>>((const float4*)x, (float4*)out,
                                           (float4*)partial);
    k2_logits<<<NCOLS / 256, 256, 0, stream>>>(partial, activ, logits, blocksums);
    k3_logit0<<<1, 128, 0, stream>>>(blocksums, logits);
    k4_sample_scatter<<<NROWS, 256, 0, stream>>>(logits, stdp, out);
}

// Round 2
// 351.517 us; speedup vs baseline: 1.0223x; 1.0223x over previous
//
#include <hip/hip_runtime.h>
#include <math.h>

// Problem constants (batch=1024, n=32768), fixed by setup_inputs().
#define NROWS 1024
#define NCOLS 32768
#define NC4   (NCOLS / 4)          // 8192 float4 per row

// ---------------------------------------------------------------------------
// Threefry-2x32 with key (0, 42)  == jax.random.key(42) raw key data.
// Exact JAX schedule (verified bit-exact vs reference in R0: absmax 0.0).
// ---------------------------------------------------------------------------
__device__ __forceinline__ void tf_round(unsigned &x0, unsigned &x1, int r) {
    x0 += x1;
    x1 = (x1 << r) | (x1 >> (32 - r));
    x1 ^= x0;
}

__device__ __forceinline__ void threefry2x32_key0_42(unsigned &x0, unsigned &x1) {
    const unsigned k0 = 0u;
    const unsigned k1 = 42u;
    const unsigned k2 = 0x1BD11BDAu ^ k0 ^ k1;
    x0 += k0; x1 += k1;
    tf_round(x0, x1, 13); tf_round(x0, x1, 15); tf_round(x0, x1, 26); tf_round(x0, x1, 6);
    x0 += k1; x1 += k2 + 1u;
    tf_round(x0, x1, 17); tf_round(x0, x1, 29); tf_round(x0, x1, 16); tf_round(x0, x1, 24);
    x0 += k2; x1 += k0 + 2u;
    tf_round(x0, x1, 13); tf_round(x0, x1, 15); tf_round(x0, x1, 26); tf_round(x0, x1, 6);
    x0 += k0; x1 += k1 + 3u;
    tf_round(x0, x1, 17); tf_round(x0, x1, 29); tf_round(x0, x1, 16); tf_round(x0, x1, 24);
    x0 += k1; x1 += k2 + 4u;
    tf_round(x0, x1, 13); tf_round(x0, x1, 15); tf_round(x0, x1, 26); tf_round(x0, x1, 6);
    x0 += k2; x1 += k0 + 5u;
}

// ---------------------------------------------------------------------------
// k1: copy x -> out (bitwise) and accumulate per-column |x| partial sums.
// grid (32, nrb), 256 threads. rows_per_blk = NROWS/nrb chosen at launch
// from ws_size. partial layout: partial[rowblk][col].
// ---------------------------------------------------------------------------
__global__ __launch_bounds__(256) void k1_copy_colsum(
        const float4* __restrict__ x4, float4* __restrict__ out4,
        float4* __restrict__ partial4, int rows_per_blk) {
    const int t  = threadIdx.x;
    const int j4 = blockIdx.x * 256 + t;         // float4 column index [0, NC4)
    const int r0 = blockIdx.y * rows_per_blk;
    float4 acc = make_float4(0.f, 0.f, 0.f, 0.f);
    size_t base = (size_t)r0 * NC4 + j4;
    #pragma unroll 8
    for (int r = 0; r < rows_per_blk; ++r) {
        float4 v = x4[base];
        out4[base] = v;
        acc.x += fabsf(v.x); acc.y += fabsf(v.y);
        acc.z += fabsf(v.z); acc.w += fabsf(v.w);
        base += NC4;
    }
    partial4[(size_t)blockIdx.y * NC4 + j4] = acc;
}

// ---------------------------------------------------------------------------
// k2: finish column mean, EMA update, ac = exp(-5*a).
// Emits w[j] = 1/ac_j (inverse weight for the argmin-form gumbel compare)
// and block-partial sums of ac. grid 128, 256 threads.
// ---------------------------------------------------------------------------
__global__ __launch_bounds__(256) void k2_weights(
        const float* __restrict__ partial, const float* __restrict__ activ,
        float* __restrict__ w, float* __restrict__ blocksums, int nrb) {
    const int t = threadIdx.x;
    const int j = blockIdx.x * 256 + t;
    float s = 0.f;
    for (int rb = 0; rb < nrb; ++rb) s += partial[rb * NCOLS + j];
    float m  = s * (1.0f / (float)NROWS);
    float a  = 0.97f * activ[j] + 0.03f * m;     // EMA buffer update
    float ac = expf(-5.0f * a);
    w[j] = 1.0f / ac;                            // inverse weight
    __shared__ float red[256];
    red[t] = ac;
    __syncthreads();
    for (int off = 128; off > 0; off >>= 1) {
        if (t < off) red[t] += red[t + off];
        __syncthreads();
    }
    if (t == 0) blocksums[blockIdx.x] = red[0];
}

// ---------------------------------------------------------------------------
// k3: s = sum(blocksums); w[0] = 1/(4000*s). 1 block, 128 threads.
// ---------------------------------------------------------------------------
__global__ __launch_bounds__(128) void k3_w0(
        const float* __restrict__ blocksums, float* __restrict__ w) {
    const int t = threadIdx.x;
    __shared__ float red[128];
    red[t] = blocksums[t];
    __syncthreads();
    for (int off = 64; off > 0; off >>= 1) {
        if (t < off) red[t] += red[t + off];
        __syncthreads();
    }
    if (t == 0) w[0] = 1.0f / (red[0] * 4000.0f);
}

// ---------------------------------------------------------------------------
// k4: per-row categorical sample via argmin-form gumbel:
//   argmax_j [logit_j + gumbel_j] == argmin_j [(-log2 u_j) * w_j]
// (strictly monotone transform; w_j = 1/ac_j > 0). One v_log_f32 per
// element instead of two precise logf — ~2.8x fewer VALU instrs.
// One block per row, 256 threads, 128 columns/thread.
// ---------------------------------------------------------------------------
__global__ __launch_bounds__(256) void k4_sample_scatter(
        const float* __restrict__ w, const float* __restrict__ stdp,
        float* __restrict__ out) {
    const int t   = threadIdx.x;
    const int row = blockIdx.x;
    const unsigned cbase = (unsigned)row * (unsigned)NCOLS;
    float best = INFINITY;
    int   bi   = 0x7FFFFFFF;

    for (int j = t; j < NCOLS; j += 256) {
        unsigned x0 = 0u;
        unsigned x1 = cbase + (unsigned)j;
        threefry2x32_key0_42(x0, x1);
        unsigned bits = x0 ^ x1;
        // uniform in [tiny, 1):  bitcast((bits>>9)|0x3f800000) - 1, clamp
        float u = __uint_as_float((bits >> 9) | 0x3f800000u) - 1.0f;
        u = fmaxf(u, 1.17549435e-38f);
        float tpos = -__log2f(u);                // -log2(u) > 0, v_log_f32
        float val  = tpos * w[j];
        if (val < best) { best = val; bi = j; }  // strict < keeps earliest j
    }

    __shared__ float sv[256];
    __shared__ int   si[256];
    sv[t] = best; si[t] = bi;
    __syncthreads();
    for (int off = 128; off > 0; off >>= 1) {
        if (t < off) {
            float ov = sv[t + off]; int oi = si[t + off];
            if (ov < sv[t] || (ov == sv[t] && oi < si[t])) { sv[t] = ov; si[t] = oi; }
        }
        __syncthreads();
    }
    if (t == 0) {
        int r = si[0];
        if (r > 0 && r < NCOLS) {
            out[(size_t)row * NCOLS + r] += stdp[0];   // std * (r > 0)
        }
    }
}

// ---------------------------------------------------------------------------
extern "C" void kernel_launch(void* const* d_in, const int* in_sizes, int n_in,
                              void* d_out, int out_size, void* d_ws, size_t ws_size,
                              hipStream_t stream) {
    (void)in_sizes; (void)n_in; (void)out_size;
    const float* x     = (const float*)d_in[0];   // [1024, 1, 32768] f32
    const float* activ = (const float*)d_in[1];   // [1, 32768] f32
    const float* stdp  = (const float*)d_in[2];   // [1] f32
    float* out = (float*)d_out;                   // [1024, 1, 32768] f32
    float* ws  = (float*)d_ws;

    // Pick row-block count from available workspace (deterministic per call).
    // Need (nrb*NCOLS + NCOLS + 256) floats.
    int nrb = 16;
    if (ws_size >= (size_t)(32 * NCOLS + NCOLS + 256) * sizeof(float)) nrb = 32;
    const int rows_per_blk = NROWS / nrb;

    // Workspace layout (floats): partial[nrb*NCOLS] | w[NCOLS] | blocksums[128]
    float* partial   = ws;
    float* wbuf      = ws + (size_t)nrb * NCOLS;
    float* blocksums = wbuf + NCOLS;

    dim3 g1(NC4 / 256, nrb);
    k1_copy_colsum<<<g1, 256, 0, stream>>>((const float4*)x, (float4*)out,
                                           (float4*)partial, rows_per_blk);
    k2_weights<<<NCOLS / 256, 256, 0, stream>>>(partial, activ, wbuf, blocksums, nrb);
    k3_w0<<<1, 128, 0, stream>>>(blocksums, wbuf);
    k4_sample_scatter<<<NROWS, 256, 0, stream>>>(wbuf, stdp, out);
}

// Round 3
// 302.391 us; speedup vs baseline: 1.1884x; 1.1625x over previous
//
#include <hip/hip_runtime.h>
#include <math.h>

// Problem constants (batch=1024, n=32768), fixed by setup_inputs().
#define NROWS 1024
#define NCOLS 32768
#define NC4   (NCOLS / 4)          // 8192 float4 per row
#define KCAND 16                   // candidate slots per row
#define TH_BITS 0xFFFC0000u        // bits >= this  <=>  u >= 1 - 2^-14
// Certified lower bound on -log2f(u) for any screened-OUT element
// (u <= 1-2^-14 -> t >= 8.8055e-5). Guard uses 7.9e-5 (extra 0.9x safety).
#define T_GUARD 7.9e-5f

// ---------------------------------------------------------------------------
// Threefry-2x32 with key (0, 42)  == jax.random.key(42) raw key data.
// Exact JAX partitionable scheme (verified bit-exact in R1/R2: absmax 0.0).
// ---------------------------------------------------------------------------
__device__ __forceinline__ void tf_round(unsigned &x0, unsigned &x1, int r) {
    x0 += x1;
    x1 = __builtin_rotateleft32(x1, r);   // guarantee v_alignbit_b32
    x1 ^= x0;
}

__device__ __forceinline__ void threefry2x32_key0_42(unsigned &x0, unsigned &x1) {
    const unsigned k0 = 0u;
    const unsigned k1 = 42u;
    const unsigned k2 = 0x1BD11BDAu ^ k0 ^ k1;
    x0 += k0; x1 += k1;
    tf_round(x0, x1, 13); tf_round(x0, x1, 15); tf_round(x0, x1, 26); tf_round(x0, x1, 6);
    x0 += k1; x1 += k2 + 1u;
    tf_round(x0, x1, 17); tf_round(x0, x1, 29); tf_round(x0, x1, 16); tf_round(x0, x1, 24);
    x0 += k2; x1 += k0 + 2u;
    tf_round(x0, x1, 13); tf_round(x0, x1, 15); tf_round(x0, x1, 26); tf_round(x0, x1, 6);
    x0 += k0; x1 += k1 + 3u;
    tf_round(x0, x1, 17); tf_round(x0, x1, 29); tf_round(x0, x1, 16); tf_round(x0, x1, 24);
    x0 += k1; x1 += k2 + 4u;
    tf_round(x0, x1, 13); tf_round(x0, x1, 15); tf_round(x0, x1, 26); tf_round(x0, x1, 6);
    x0 += k2; x1 += k0 + 5u;
}

__device__ __forceinline__ float bits_to_u(unsigned bits) {
    float u = __uint_as_float((bits >> 9) | 0x3f800000u) - 1.0f;
    return fmaxf(u, 1.17549435e-38f);
}

// ---------------------------------------------------------------------------
// kF: FUSED copy/colsum (HBM-bound) + threefry candidate scan (VALU-bound).
// 1024 blocks x 256 threads. Block b scans row b (all blocks); blocks
// b < nrb*32 also copy a (256 j4-cols x rows_per_blk) slice. Even/odd
// blocks run the two phases in opposite order to guarantee pipe mixing.
// Scan fast path per element: threefry + xor + 1 integer compare.
// ---------------------------------------------------------------------------
__global__ __launch_bounds__(256) void kF(
        const float4* __restrict__ x4, float4* __restrict__ out4,
        float4* __restrict__ partial4, unsigned* __restrict__ bits0,
        unsigned* __restrict__ cnt, uint2* __restrict__ cand, int nrb) {
    const int b = blockIdx.x;
    const int t = threadIdx.x;
    const int rpb = NROWS / nrb;

    auto copy_part = [&]() {
        if (b >= nrb * 32) return;
        const int bx = b & 31, by = b >> 5;
        const int j4 = bx * 256 + t;
        size_t base = (size_t)(by * rpb) * NC4 + j4;
        float4 acc = make_float4(0.f, 0.f, 0.f, 0.f);
        #pragma unroll 8
        for (int r = 0; r < rpb; ++r) {
            float4 v = x4[base];
            out4[base] = v;
            acc.x += fabsf(v.x); acc.y += fabsf(v.y);
            acc.z += fabsf(v.z); acc.w += fabsf(v.w);
            base += NC4;
        }
        partial4[(size_t)by * NC4 + j4] = acc;
    };

    auto scan_part = [&]() {
        const unsigned cbase = (unsigned)b * (unsigned)NCOLS;
        #pragma unroll 2
        for (int i = 0; i < NCOLS / 256; ++i) {
            const int j = t + (i << 8);
            unsigned x0 = 0u, x1 = cbase + (unsigned)j;
            threefry2x32_key0_42(x0, x1);
            const unsigned bits = x0 ^ x1;
            if (j == 0) {
                bits0[b] = bits;
            } else if (bits >= TH_BITS) {
                unsigned pos = atomicAdd(&cnt[b], 1u);
                if (pos < KCAND) cand[b * KCAND + pos] = make_uint2((unsigned)j, bits);
            }
        }
    };

    if (b & 1) { scan_part(); copy_part(); }
    else       { copy_part(); scan_part(); }
}

// ---------------------------------------------------------------------------
// k2: column mean, EMA update, ac = exp(-5*a), w = 1/ac; block sums of ac
// and block mins of w over j>=1. grid 128 x 256.
// ---------------------------------------------------------------------------
__global__ __launch_bounds__(256) void k2_weights(
        const float* __restrict__ partial, const float* __restrict__ activ,
        float* __restrict__ w, float* __restrict__ blocksums,
        float* __restrict__ blockmins, int nrb) {
    const int t = threadIdx.x;
    const int j = blockIdx.x * 256 + t;
    float s = 0.f;
    for (int rb = 0; rb < nrb; ++rb) s += partial[rb * NCOLS + j];
    float m  = s * (1.0f / (float)NROWS);
    float a  = 0.97f * activ[j] + 0.03f * m;     // EMA buffer update
    float ac = expf(-5.0f * a);
    float wj = 1.0f / ac;
    w[j] = wj;
    __shared__ float reds[256];
    __shared__ float redm[256];
    reds[t] = ac;
    redm[t] = (j == 0) ? INFINITY : wj;
    __syncthreads();
    for (int off = 128; off > 0; off >>= 1) {
        if (t < off) {
            reds[t] += reds[t + off];
            redm[t] = fminf(redm[t], redm[t + off]);
        }
        __syncthreads();
    }
    if (t == 0) { blocksums[blockIdx.x] = reds[0]; blockmins[blockIdx.x] = redm[0]; }
}

// ---------------------------------------------------------------------------
// k3: s = sum(blocksums); w[0] = 1/(4000*s); wmin = min(blockmins).
// ---------------------------------------------------------------------------
__global__ __launch_bounds__(128) void k3_scalars(
        const float* __restrict__ blocksums, const float* __restrict__ blockmins,
        float* __restrict__ w, float* __restrict__ wminp) {
    const int t = threadIdx.x;
    __shared__ float reds[128];
    __shared__ float redm[128];
    reds[t] = blocksums[t];
    redm[t] = blockmins[t];
    __syncthreads();
    for (int off = 64; off > 0; off >>= 1) {
        if (t < off) {
            reds[t] += reds[t + off];
            redm[t] = fminf(redm[t], redm[t + off]);
        }
        __syncthreads();
    }
    if (t == 0) { w[0] = 1.0f / (reds[0] * 4000.0f); wminp[0] = redm[0]; }
}

// ---------------------------------------------------------------------------
// k4b: per-row winner resolution. Normal path: val0 (exact, same formula as
// R2) vs <=16 candidates — serial on thread 0, ~20 ops. Guard: if val0 is
// large enough that a screened-out element could win, or candidate overflow,
// do an exact full rescan of the row (rare; correctness never depends on
// the screen margin). 1024 blocks x 64 threads.
// ---------------------------------------------------------------------------
__global__ __launch_bounds__(64) void k4b_resolve(
        const float* __restrict__ w, const unsigned* __restrict__ bits0,
        const unsigned* __restrict__ cnt, const uint2* __restrict__ cand,
        const float* __restrict__ wminp, const float* __restrict__ stdp,
        float* __restrict__ out) {
    const int r = blockIdx.x;
    const int t = threadIdx.x;
    const float w0   = w[0];
    const float wmin = wminp[0];
    const float val0 = -__log2f(bits_to_u(bits0[r])) * w0;
    const unsigned c = cnt[r];
    const bool slow = (c > KCAND) || !(val0 < T_GUARD * wmin);

    if (!slow) {
        if (t == 0 && c > 0) {
            float best = INFINITY;
            int   bi   = 0x7FFFFFFF;
            for (int k = 0; k < (int)c; ++k) {
                uint2 cd = cand[r * KCAND + k];
                float v = -__log2f(bits_to_u(cd.y)) * w[cd.x];
                int   j = (int)cd.x;
                if (v < best || (v == best && j < bi)) { best = v; bi = j; }
            }
            if (best < val0 && bi > 0 && bi < NCOLS)
                out[(size_t)r * NCOLS + bi] += stdp[0];
        }
        return;
    }

    // ---- slow path: exact rescan of the whole row ----
    const unsigned cbase = (unsigned)r * (unsigned)NCOLS;
    float best = INFINITY;
    int   bi   = 0x7FFFFFFF;
    for (int j = t; j < NCOLS; j += 64) {
        if (j == 0) continue;
        unsigned x0 = 0u, x1 = cbase + (unsigned)j;
        threefry2x32_key0_42(x0, x1);
        float v = -__log2f(bits_to_u(x0 ^ x1)) * w[j];
        if (v < best) { best = v; bi = j; }
    }
    __shared__ float sv[64];
    __shared__ int   si[64];
    sv[t] = best; si[t] = bi;
    __syncthreads();
    for (int off = 32; off > 0; off >>= 1) {
        if (t < off) {
            float ov = sv[t + off]; int oi = si[t + off];
            if (ov < sv[t] || (ov == sv[t] && oi < si[t])) { sv[t] = ov; si[t] = oi; }
        }
        __syncthreads();
    }
    if (t == 0) {
        if (sv[0] < val0 && si[0] > 0 && si[0] < NCOLS)
            out[(size_t)r * NCOLS + si[0]] += stdp[0];
    }
}

// ---------------------------------------------------------------------------
extern "C" void kernel_launch(void* const* d_in, const int* in_sizes, int n_in,
                              void* d_out, int out_size, void* d_ws, size_t ws_size,
                              hipStream_t stream) {
    (void)in_sizes; (void)n_in; (void)out_size;
    const float* x     = (const float*)d_in[0];   // [1024, 1, 32768] f32
    const float* activ = (const float*)d_in[1];   // [1, 32768] f32
    const float* stdp  = (const float*)d_in[2];   // [1] f32
    float* out = (float*)d_out;                   // [1024, 1, 32768] f32
    char*  ws  = (char*)d_ws;

    // Fixed tail (bytes): w[NCOLS] f32 | blocksums[128] | blockmins[128] |
    // wmin[1] | bits0[1024] u32 | cnt[1024] u32 | cand[1024*KCAND] uint2
    const size_t tail_bytes = (size_t)NCOLS * 4 + 128 * 4 + 128 * 4 + 4
                            + NROWS * 4 + NROWS * 4 + (size_t)NROWS * KCAND * 8;
    int nrb = 16;
    if (ws_size >= (size_t)32 * NCOLS * 4 + tail_bytes) nrb = 32;

    float*    partial   = (float*)ws;
    float*    wbuf      = (float*)(ws + (size_t)nrb * NCOLS * 4);
    float*    blocksums = wbuf + NCOLS;
    float*    blockmins = blocksums + 128;
    float*    wminp     = blockmins + 128;
    unsigned* bits0     = (unsigned*)(wminp + 1);
    unsigned* cnt       = bits0 + NROWS;
    uint2*    cand      = (uint2*)(cnt + NROWS);

    hipMemsetAsync(cnt, 0, NROWS * sizeof(unsigned), stream);
    kF<<<NROWS, 256, 0, stream>>>((const float4*)x, (float4*)out,
                                  (float4*)partial, bits0, cnt, cand, nrb);
    k2_weights<<<NCOLS / 256, 256, 0, stream>>>(partial, activ, wbuf,
                                                blocksums, blockmins, nrb);
    k3_scalars<<<1, 128, 0, stream>>>(blocksums, blockmins, wbuf, wminp);
    k4b_resolve<<<NROWS, 64, 0, stream>>>(wbuf, bits0, cnt, cand, wminp,
                                          stdp, out);
}